// Round 12
// baseline (188.431 us; speedup 1.0000x reference)
//
#include <hip/hip_runtime.h>
#include <math.h>

#define B_  128
#define N_  21
#define D_  300
#define NPAIRS 231                  // upper-tri incl diag
#define NPAIR_TOT (B_ * NPAIRS)     // 29568
#define GRID_E (NPAIR_TOT / 64)     // 462 blocks x 4 waves x 16 pairs
#define NROWS (B_ * N_)             // 2688
#define DP  320

typedef __attribute__((ext_vector_type(8))) short short8v;
typedef __attribute__((ext_vector_type(4))) float f32x4;

__device__ __forceinline__ float lrelu(float v) { return v > 0.f ? v : 0.01f * v; }

__device__ __forceinline__ unsigned short f2bf(float f) {
    unsigned u = __builtin_bit_cast(unsigned, f);
    u += 0x7FFFu + ((u >> 16) & 1u);
    return (unsigned short)(u >> 16);
}
__device__ __forceinline__ float bf2f(unsigned short h) {
    unsigned u = ((unsigned)h) << 16;
    return __builtin_bit_cast(float, u);
}

// ---------------------------------------------------------------------------
// One prep kernel: edge weights (2 layers) + node weights -> bf16 hi/lo.
__global__ __launch_bounds__(256) void prep_all(
    const float* __restrict__ e00, const float* __restrict__ e01, const float* __restrict__ e02,
    const float* __restrict__ e10, const float* __restrict__ e11, const float* __restrict__ e12,
    const float* __restrict__ n0n, const float* __restrict__ n0r,
    const float* __restrict__ n1n, const float* __restrict__ n1r,
    unsigned short* __restrict__ ewb, unsigned short* __restrict__ nwb, int do_node)
{
    int idx = blockIdx.x * 256 + threadIdx.x;   // grid 2624 -> 671744 exact
    float v; unsigned short *ph, *pl; int off;
    if (idx < 262144) {
        int l = idx >> 17;
        int t = idx & 131071;
        unsigned short* blk = ewb + (size_t)l * 262144;
        const float* w0 = l ? e10 : e00;
        const float* w1 = l ? e11 : e01;
        const float* w2 = l ? e12 : e02;
        if (t < 81920) {
            int n = t / 320, k = t - n * 320;
            v = (k < 300) ? w0[n * 300 + k] : 0.f;
            ph = blk; pl = blk + 81920; off = t;
        } else if (t < 114688) {
            int r = t - 81920; v = w1[r];
            ph = blk + 163840; pl = blk + 196608; off = r;
        } else {
            int r = t - 114688; v = w2[r];
            ph = blk + 229376; pl = blk + 245760; off = r;
        }
    } else {
        if (!do_node) return;
        int t = idx - 262144;                    // 0 .. 409599
        int l = t / 204800;
        int r = t - l * 204800;
        int mat = r / 102400;
        int q = r - mat * 102400;
        int n = q / 320, k = q - n * 320;
        const float* src = l ? (mat ? n1r : n1n) : (mat ? n0r : n0n);
        v = (n < 300 && k < 300) ? src[n * 300 + k] : 0.f;
        unsigned short* blk = nwb + (size_t)l * 409600;
        ph = blk + mat * 204800; pl = ph + 102400; off = q;
    }
    unsigned short hb = f2bf(v);
    ph[off] = hb; pl[off] = f2bf(v - bf2f(hb));
}

// ---------------------------------------------------------------------------
// 4-lane-group transpose (by value; verified rounds 6-11).
__device__ __forceinline__ short8v mk_frag(uint2 tlo, uint2 thi,
                                           int s1, int s2, bool hif)
{
    unsigned a0 = (unsigned)__shfl((int)tlo.x, s1);
    unsigned b0 = (unsigned)__shfl((int)thi.x, s1);
    unsigned a1 = (unsigned)__shfl((int)tlo.y, s1);
    unsigned b1 = (unsigned)__shfl((int)thi.y, s1);
    unsigned a2 = (unsigned)__shfl((int)tlo.x, s2);
    unsigned b2 = (unsigned)__shfl((int)thi.x, s2);
    unsigned a3 = (unsigned)__shfl((int)tlo.y, s2);
    unsigned b3 = (unsigned)__shfl((int)thi.y, s2);
    union { unsigned u[4]; short8v v; } r;
    r.u[0] = hif ? b0 : a0; r.u[1] = hif ? b1 : a1;
    r.u[2] = hif ? b2 : a2; r.u[3] = hif ? b3 : a3;
    return r.v;
}

// ---------------------------------------------------------------------------
// Edge MLP (round-11 proven): 4 waves x 16 pairs; weights staged per-k-chunk
// into LDS dbuf via global_load_lds; full unroll on G2/G3 (no scratch).
__global__ __launch_bounds__(256, 2) void edge_mfma(
    const float* __restrict__ x,
    const unsigned short* __restrict__ w0h, const unsigned short* __restrict__ w0l,
    const unsigned short* __restrict__ w1h, const unsigned short* __restrict__ w1l,
    const unsigned short* __restrict__ w2h, const unsigned short* __restrict__ w2l,
    const float* __restrict__ wo, const float* __restrict__ bo,
    float* __restrict__ adjraw)
{
    __shared__ __align__(16) unsigned short ldsW[2][16384];

    const int tid  = threadIdx.x;
    const int lane = tid & 63;
    const int w    = tid >> 6;
    const int l15  = lane & 15;
    const int l4   = lane >> 4;

    const int p = blockIdx.x * 64 + w * 16 + l15;
    int bb = p / NPAIRS;
    int u  = p - bb * NPAIRS;
    int ii = 0;
    while (u >= N_ - ii) { u -= N_ - ii; ++ii; }
    int jj = ii + u;
    const float* xi = x + ((size_t)bb * N_ + ii) * D_;
    const float* xj = x + ((size_t)bb * N_ + jj) * D_;

    const int s1 = (lane & 15) | ((lane & 16) << 1);
    const int s2 = s1 + 16;
    const bool hif = (l4 >> 1) != 0;

    auto stage_g1 = [&](int c, int sel) {
        #pragma unroll
        for (int i = 0; i < 4; ++i) {
            const int tile = i * 4 + w;
            const size_t g = (size_t)(tile * 16 + l15) * 320 + c * 32 + l4 * 8;
            __builtin_amdgcn_global_load_lds((const unsigned int*)(w0h + g),
                (unsigned int*)(&ldsW[sel][tile * 512]), 16, 0, 0);
            __builtin_amdgcn_global_load_lds((const unsigned int*)(w0l + g),
                (unsigned int*)(&ldsW[sel][8192 + tile * 512]), 16, 0, 0);
        }
    };
    auto stage_g2 = [&](int c, int sel) {
        #pragma unroll
        for (int i = 0; i < 2; ++i) {
            const int tile = i * 4 + w;
            const size_t g = (size_t)(tile * 16 + l15) * 256 + c * 32 + l4 * 8;
            __builtin_amdgcn_global_load_lds((const unsigned int*)(w1h + g),
                (unsigned int*)(&ldsW[sel][tile * 512]), 16, 0, 0);
            __builtin_amdgcn_global_load_lds((const unsigned int*)(w1l + g),
                (unsigned int*)(&ldsW[sel][8192 + tile * 512]), 16, 0, 0);
        }
    };
    auto stage_g3 = [&](int c, int sel) {
        #pragma unroll
        for (int i = 0; i < 2; ++i) {
            const int tile = i * 4 + w;
            const size_t g = (size_t)(tile * 16 + l15) * 128 + c * 32 + l4 * 8;
            __builtin_amdgcn_global_load_lds((const unsigned int*)(w2h + g),
                (unsigned int*)(&ldsW[sel][tile * 512]), 16, 0, 0);
            __builtin_amdgcn_global_load_lds((const unsigned int*)(w2l + g),
                (unsigned int*)(&ldsW[sel][8192 + tile * 512]), 16, 0, 0);
        }
    };

    // ---------------- G1: h0 = w0 @ xij^T, K=320 (10 chunks) ----------------
    f32x4 acc[16];
    #pragma unroll
    for (int t = 0; t < 16; ++t) acc[t] = (f32x4){0.f, 0.f, 0.f, 0.f};

    stage_g1(0, 0);
    __syncthreads();

    #pragma unroll 1
    for (int c = 0; c < 10; ++c) {
        const int sel = c & 1;
        if (c < 9) stage_g1(c + 1, sel ^ 1);
        else       stage_g2(0, sel ^ 1);

        const int d0 = c * 32 + l4 * 8;
        float v[8];
        if (c < 9) {
            float4 a0 = *(const float4*)(xi + d0);
            float4 a1 = *(const float4*)(xi + d0 + 4);
            float4 b0 = *(const float4*)(xj + d0);
            float4 b1 = *(const float4*)(xj + d0 + 4);
            #pragma unroll
            for (int e = 0; e < 4; ++e) {
                v[e]     = expf(-fabsf((&a0.x)[e] - (&b0.x)[e]));
                v[4 + e] = expf(-fabsf((&a1.x)[e] - (&b1.x)[e]));
            }
        } else {
            #pragma unroll
            for (int e = 0; e < 8; ++e) {
                int d = d0 + e;
                v[e] = (d < D_) ? expf(-fabsf(xi[d] - xj[d])) : 0.f;
            }
        }
        short8v bh, bl;
        #pragma unroll
        for (int e = 0; e < 8; ++e) {
            unsigned short hb = f2bf(v[e]);
            bh[e] = (short)hb;
            bl[e] = (short)f2bf(v[e] - bf2f(hb));
        }

        #pragma unroll
        for (int t = 0; t < 16; ++t) {
            short8v wh = *(const short8v*)(&ldsW[sel][t * 512 + lane * 8]);
            short8v wl = *(const short8v*)(&ldsW[sel][8192 + t * 512 + lane * 8]);
            acc[t] = __builtin_amdgcn_mfma_f32_16x16x32_bf16(wh, bh, acc[t], 0, 0, 0);
            acc[t] = __builtin_amdgcn_mfma_f32_16x16x32_bf16(wh, bl, acc[t], 0, 0, 0);
            acc[t] = __builtin_amdgcn_mfma_f32_16x16x32_bf16(wl, bh, acc[t], 0, 0, 0);
        }
        __syncthreads();
    }

    uint2 hh[16], ll[16];
    #pragma unroll
    for (int t = 0; t < 16; ++t) {
        unsigned short h_[4], l_[4];
        #pragma unroll
        for (int r = 0; r < 4; ++r) {
            float f = lrelu(acc[t][r]);
            h_[r] = f2bf(f);
            l_[r] = f2bf(f - bf2f(h_[r]));
        }
        hh[t].x = (unsigned)h_[0] | ((unsigned)h_[1] << 16);
        hh[t].y = (unsigned)h_[2] | ((unsigned)h_[3] << 16);
        ll[t].x = (unsigned)l_[0] | ((unsigned)l_[1] << 16);
        ll[t].y = (unsigned)l_[2] | ((unsigned)l_[3] << 16);
    }

    // ---------------- G2: h1 = w1 @ h0^T, K=256 (8 chunks, FULL UNROLL) ----
    f32x4 acc2[8];
    #pragma unroll
    for (int t = 0; t < 8; ++t) acc2[t] = (f32x4){0.f, 0.f, 0.f, 0.f};

    #pragma unroll
    for (int ks = 0; ks < 8; ++ks) {
        const int sel = ks & 1;
        if (ks < 7) stage_g2(ks + 1, sel ^ 1);
        else        stage_g3(0, sel ^ 1);

        short8v bh = mk_frag(hh[2 * ks], hh[2 * ks + 1], s1, s2, hif);
        short8v bl = mk_frag(ll[2 * ks], ll[2 * ks + 1], s1, s2, hif);

        #pragma unroll
        for (int t = 0; t < 8; ++t) {
            short8v wh = *(const short8v*)(&ldsW[sel][t * 512 + lane * 8]);
            short8v wl = *(const short8v*)(&ldsW[sel][8192 + t * 512 + lane * 8]);
            acc2[t] = __builtin_amdgcn_mfma_f32_16x16x32_bf16(wh, bh, acc2[t], 0, 0, 0);
            acc2[t] = __builtin_amdgcn_mfma_f32_16x16x32_bf16(wh, bl, acc2[t], 0, 0, 0);
            acc2[t] = __builtin_amdgcn_mfma_f32_16x16x32_bf16(wl, bh, acc2[t], 0, 0, 0);
        }
        __syncthreads();
    }

    uint2 hh1[8], ll1[8];
    #pragma unroll
    for (int t = 0; t < 8; ++t) {
        unsigned short h_[4], l_[4];
        #pragma unroll
        for (int r = 0; r < 4; ++r) {
            float f = lrelu(acc2[t][r]);
            h_[r] = f2bf(f);
            l_[r] = f2bf(f - bf2f(h_[r]));
        }
        hh1[t].x = (unsigned)h_[0] | ((unsigned)h_[1] << 16);
        hh1[t].y = (unsigned)h_[2] | ((unsigned)h_[3] << 16);
        ll1[t].x = (unsigned)l_[0] | ((unsigned)l_[1] << 16);
        ll1[t].y = (unsigned)l_[2] | ((unsigned)l_[3] << 16);
    }

    // ---------------- G3: h2 = w2 @ h1^T, K=128 (4 chunks, FULL UNROLL) ----
    f32x4 acc3[8];
    #pragma unroll
    for (int t = 0; t < 8; ++t) acc3[t] = (f32x4){0.f, 0.f, 0.f, 0.f};

    #pragma unroll
    for (int ks = 0; ks < 4; ++ks) {
        const int sel = ks & 1;
        if (ks < 3) stage_g3(ks + 1, sel ^ 1);

        short8v bh = mk_frag(hh1[2 * ks], hh1[2 * ks + 1], s1, s2, hif);
        short8v bl = mk_frag(ll1[2 * ks], ll1[2 * ks + 1], s1, s2, hif);

        #pragma unroll
        for (int t = 0; t < 8; ++t) {
            short8v wh = *(const short8v*)(&ldsW[sel][t * 512 + lane * 8]);
            short8v wl = *(const short8v*)(&ldsW[sel][8192 + t * 512 + lane * 8]);
            acc3[t] = __builtin_amdgcn_mfma_f32_16x16x32_bf16(wh, bh, acc3[t], 0, 0, 0);
            acc3[t] = __builtin_amdgcn_mfma_f32_16x16x32_bf16(wh, bl, acc3[t], 0, 0, 0);
            acc3[t] = __builtin_amdgcn_mfma_f32_16x16x32_bf16(wl, bh, acc3[t], 0, 0, 0);
        }
        __syncthreads();
    }

    float ps = 0.f;
    #pragma unroll
    for (int t = 0; t < 8; ++t) {
        float4 wov = *(const float4*)(wo + t * 16 + l4 * 4);
        #pragma unroll
        for (int r = 0; r < 4; ++r)
            ps += lrelu(acc3[t][r]) * (&wov.x)[r];
    }
    ps += __shfl_xor(ps, 16);
    ps += __shfl_xor(ps, 32);
    if (l4 == 0) {
        float a = 1.f / (1.f + expf(-(ps + bo[0])));
        if (ii == jj) a = 0.f;
        adjraw[(size_t)bb * 441 + ii * 21 + jj] = a;
        adjraw[(size_t)bb * 441 + jj * 21 + ii] = a;
    }
}

// ---------------------------------------------------------------------------
// Node GEMM via MFMA, 64-row M-blocks: wave = 5 n-tiles x 4 m-frags, weight
// registers reused across the 4 m-frags -> weight L2 traffic /4 vs round 11.
// grid (42, 2); x staged 64x32 per chunk in LDS (xor-swizzled, dbuf).
__global__ __launch_bounds__(256, 2) void node_gemm(
    const float* __restrict__ xin,
    const unsigned short* __restrict__ wnh, const unsigned short* __restrict__ wnl,
    const unsigned short* __restrict__ wrh, const unsigned short* __restrict__ wrl,
    float* __restrict__ nbuf)
{
    __shared__ __align__(16) unsigned short sxh[2][2048], sxl[2][2048];  // 16 KB

    const int tid  = threadIdx.x;
    const int lane = tid & 63;
    const int w    = tid >> 6;
    const int l15  = lane & 15;
    const int l4   = lane >> 4;
    const int M0   = blockIdx.x * 64;
    const int mat  = blockIdx.y;

    const unsigned short* ah_base = mat ? wrh : wnh;
    const unsigned short* al_base = mat ? wrl : wnl;
    float* ob = nbuf + (size_t)mat * NROWS * DP;

    // staging: sm = row 0..63 (tid>>2), sku = 8-elem unit 0..3 (tid&3)
    const int sm  = tid >> 2;
    const int sku = tid & 3;
    const int sk  = sku * 8;
    const float* xrow = xin + (size_t)(M0 + sm) * D_;
    const int sa = sm * 32 + ((sku ^ ((sm >> 1) & 3)) << 3);

    auto stage = [&](int c, int sel) {
        const int k0 = c * 32 + sk;
        short8v hv, lv;
        if (k0 + 8 <= D_) {
            float4 a0 = *(const float4*)(xrow + k0);
            float4 a1 = *(const float4*)(xrow + k0 + 4);
            #pragma unroll
            for (int e = 0; e < 4; ++e) {
                unsigned short hb = f2bf((&a0.x)[e]);
                hv[e] = (short)hb; lv[e] = (short)f2bf((&a0.x)[e] - bf2f(hb));
                unsigned short hb2 = f2bf((&a1.x)[e]);
                hv[4 + e] = (short)hb2; lv[4 + e] = (short)f2bf((&a1.x)[e] - bf2f(hb2));
            }
        } else {
            #pragma unroll
            for (int e = 0; e < 8; ++e) {
                float f = (k0 + e < D_) ? xrow[k0 + e] : 0.f;
                unsigned short hb = f2bf(f);
                hv[e] = (short)hb; lv[e] = (short)f2bf(f - bf2f(hb));
            }
        }
        *(short8v*)(&sxh[sel][sa]) = hv;
        *(short8v*)(&sxl[sel][sa]) = lv;
    };

    f32x4 acc[20];
    #pragma unroll
    for (int t = 0; t < 20; ++t) acc[t] = (f32x4){0.f, 0.f, 0.f, 0.f};

    stage(0, 0);
    __syncthreads();

    #pragma unroll 1
    for (int c = 0; c < 10; ++c) {
        const int sel = c & 1;
        // weight registers for this chunk (reused across 4 m-frags)
        short8v wh[5], wl[5];
        const int kg = c * 32 + l4 * 8;
        #pragma unroll
        for (int t = 0; t < 5; ++t) {
            const size_t n = (size_t)((w * 5 + t) * 16 + l15);
            wh[t] = *(const short8v*)(ah_base + n * DP + kg);
            wl[t] = *(const short8v*)(al_base + n * DP + kg);
        }
        // x B-frags for the 4 m-frags
        short8v bh[4], bl[4];
        #pragma unroll
        for (int mf = 0; mf < 4; ++mf) {
            const int row = mf * 16 + l15;
            const int off = row * 32 + ((l4 ^ ((row >> 1) & 3)) << 3);
            bh[mf] = *(const short8v*)(&sxh[sel][off]);
            bl[mf] = *(const short8v*)(&sxl[sel][off]);
        }
        #pragma unroll
        for (int t = 0; t < 5; ++t) {
            #pragma unroll
            for (int mf = 0; mf < 4; ++mf) {
                acc[t*4+mf] = __builtin_amdgcn_mfma_f32_16x16x32_bf16(wh[t], bh[mf], acc[t*4+mf], 0, 0, 0);
                acc[t*4+mf] = __builtin_amdgcn_mfma_f32_16x16x32_bf16(wh[t], bl[mf], acc[t*4+mf], 0, 0, 0);
                acc[t*4+mf] = __builtin_amdgcn_mfma_f32_16x16x32_bf16(wl[t], bh[mf], acc[t*4+mf], 0, 0, 0);
            }
        }
        if (c < 9) stage(c + 1, sel ^ 1);
        __syncthreads();
    }

    #pragma unroll
    for (int t = 0; t < 5; ++t) {
        const int n0 = (w * 5 + t) * 16 + l4 * 4;
        #pragma unroll
        for (int mf = 0; mf < 4; ++mf) {
            float4 v;
            v.x = acc[t*4+mf][0]; v.y = acc[t*4+mf][1];
            v.z = acc[t*4+mf][2]; v.w = acc[t*4+mf][3];
            *(float4*)(ob + (size_t)(M0 + mf * 16 + l15) * DP + n0) = v;
        }
    }
}

// ---------------------------------------------------------------------------
// Per-batch fused top-k + combine: one block per b, P panel read ONCE.
// out[t,o] = lrelu((sum_s A[t][s]*P[s][o] + rs_t*(bn+e0))*0.2 + R[t][o] + br)
__global__ __launch_bounds__(320) void node_combine(
    const float* __restrict__ adjraw, const float* __restrict__ nbuf,
    const float* __restrict__ bn, const float* __restrict__ br,
    const float* __restrict__ eemb, float* __restrict__ out)
{
    const int b = blockIdx.x;
    const int tid = threadIdx.x;
    __shared__ float sadj[N_][24];
    __shared__ float sA[N_][24];
    __shared__ float srs[N_];

    for (int it = tid; it < N_ * N_; it += 320) {
        int t = it / N_, s = it - (it / N_) * N_;
        sadj[t][s] = adjraw[(size_t)b * 441 + it];
    }
    __syncthreads();
    if (tid < N_) {
        // top-5 for row tid (lax.top_k tie-break: lowest index wins)
        unsigned used = 0;
        for (int r = 0; r < 5; ++r) {
            float best = -1.f; int bi = 0;
            for (int j = 0; j < N_; ++j) {
                if (used & (1u << j)) continue;
                if (sadj[tid][j] > best) { best = sadj[tid][j]; bi = j; }
            }
            used |= (1u << bi);
        }
        float rs = 0.f;
        for (int j = 0; j < N_; ++j) {
            float m = ((used >> j) & 1u) ? sadj[tid][j] : 0.f;
            sA[tid][j] = m; rs += m;
        }
        srs[tid] = rs;
    }
    __syncthreads();

    const int o = tid;
    if (o < D_) {
        const float* Pb = nbuf + (size_t)b * N_ * DP;
        const float* Rb = nbuf + (size_t)NROWS * DP + (size_t)b * N_ * DP;
        float pr[N_];
        #pragma unroll
        for (int s = 0; s < N_; ++s) pr[s] = Pb[(size_t)s * DP + o];
        const float bn_o = bn[o], br_o = br[o];
        const float add_o = bn_o + eemb[o];
        #pragma unroll
        for (int t = 0; t < N_; ++t) {
            float m = 0.f;
            #pragma unroll
            for (int s = 0; s < N_; ++s) m += sA[t][s] * pr[s];
            out[((size_t)b * N_ + t) * D_ + o] =
                lrelu((m + srs[t] * add_o) * 0.2f + Rb[(size_t)t * DP + o] + br_o);
        }
    }
}

// ---------------------------------------------------------------------------
// Fallback path (ws too small): top-k + fp32 node kernel
__global__ __launch_bounds__(64) void topk_kernel(
    const float* __restrict__ adjraw, float* __restrict__ A)
{
    const int row = blockIdx.x;
    const int lane = threadIdx.x;
    __shared__ float sadj[32];
    __shared__ unsigned s_used;
    if (lane < N_) sadj[lane] = adjraw[row * N_ + lane];
    __syncthreads();
    if (lane == 0) {
        unsigned used = 0;
        for (int r = 0; r < 5; ++r) {
            float best = -1.f; int bi = 0;
            for (int j = 0; j < N_; ++j) {
                if (used & (1u << j)) continue;
                if (sadj[j] > best) { best = sadj[j]; bi = j; }
            }
            used |= (1u << bi);
        }
        s_used = used;
    }
    __syncthreads();
    if (lane < N_)
        A[row * N_ + lane] = ((s_used >> lane) & 1u) ? sadj[lane] : 0.f;
}

__global__ __launch_bounds__(320) void node_kernel(
    const float* __restrict__ xin, const float* __restrict__ A,
    const float* __restrict__ wn, const float* __restrict__ bn,
    const float* __restrict__ wr, const float* __restrict__ br,
    const float* __restrict__ eemb, float* __restrict__ out)
{
    const int b = blockIdx.x;
    const int tid = threadIdx.x;
    __shared__ float sx[N_][304];
    __shared__ float sA[N_][24];
    __shared__ float srs[N_];

    const float* xb = xin + (size_t)b * N_ * D_;
    for (int it = tid; it < N_ * D_; it += 320) {
        int j = it / D_, d = it - (it / D_) * D_;
        sx[j][d] = xb[it];
    }
    for (int it = tid; it < N_ * N_; it += 320) {
        int t = it / N_, s = it - (it / N_) * N_;
        sA[t][s] = A[((size_t)b * N_ + t) * N_ + s];
    }
    __syncthreads();
    if (tid < N_) {
        float s = 0.f;
        #pragma unroll
        for (int j = 0; j < N_; ++j) s += sA[tid][j];
        srs[tid] = s;
    }
    __syncthreads();

    const int o = tid;
    if (o < D_) {
        float nacc[N_], racc[N_];
        #pragma unroll
        for (int j = 0; j < N_; ++j) { nacc[j] = 0.f; racc[j] = 0.f; }
        const float* wnr = wn + (size_t)o * D_;
        const float* wrr = wr + (size_t)o * D_;
        for (int k4 = 0; k4 < D_; k4 += 4) {
            float4 wn4 = *(const float4*)(wnr + k4);
            float4 wr4 = *(const float4*)(wrr + k4);
            #pragma unroll
            for (int j = 0; j < N_; ++j) {
                float4 xv = *(const float4*)(&sx[j][k4]);
                nacc[j] += wn4.x * xv.x; nacc[j] += wn4.y * xv.y;
                nacc[j] += wn4.z * xv.z; nacc[j] += wn4.w * xv.w;
                racc[j] += wr4.x * xv.x; racc[j] += wr4.y * xv.y;
                racc[j] += wr4.z * xv.z; racc[j] += wr4.w * xv.w;
            }
        }
        const float bn_o = bn[o], br_o = br[o], e0_o = eemb[o];
        const float add_o = bn_o + e0_o;
        #pragma unroll
        for (int t = 0; t < N_; ++t) {
            float m = 0.f;
            #pragma unroll
            for (int s = 0; s < N_; ++s) m += sA[t][s] * nacc[s];
            out[((size_t)b * N_ + t) * D_ + o] =
                lrelu((m + srs[t] * add_o) * 0.2f + racc[t] + br_o);
        }
    }
}

// ---------------------------------------------------------------------------
extern "C" void kernel_launch(void* const* d_in, const int* in_sizes, int n_in,
                              void* d_out, int out_size, void* d_ws, size_t ws_size,
                              hipStream_t stream)
{
    const float* x0 = (const float*)d_in[0];
    auto L = [&](int l, int k) { return (const float*)d_in[1 + l * 10 + k]; };

    // ws layout:
    //   adjraw @0        (225,792)
    //   A      @256KB    (225,792)               (fallback only)
    //   edge w @512KB    (2 x 512KB)             -> ends 1,572,864
    //   node w @1.5MB    (2 x 819,200)           -> ends 3,211,264
    //   nbuf   @3,211,264 (6,881,280)            -> ends 10,092,544
    float* adjraw = (float*)d_ws;
    float* A      = (float*)((char*)d_ws + 262144);
    unsigned short* ewb = (unsigned short*)((char*)d_ws + 524288);
    unsigned short* nwb = (unsigned short*)((char*)d_ws + 1572864);
    float* nbuf   = (float*)((char*)d_ws + 3211264);
    const size_t WS_NEED = 10092544;
    const bool newnode = (ws_size >= WS_NEED);

    prep_all<<<2624, 256, 0, stream>>>(
        L(0,0), L(0,1), L(0,2), L(1,0), L(1,1), L(1,2),
        L(0,5), L(0,7), L(1,5), L(1,7), ewb, nwb, newnode ? 1 : 0);

    for (int l = 0; l < 2; ++l) {
        const float* xin = (l == 0) ? x0 : (const float*)d_out;
        unsigned short* blk = ewb + (size_t)l * 262144;
        edge_mfma<<<GRID_E, 256, 0, stream>>>(xin,
            blk, blk + 81920, blk + 163840, blk + 196608, blk + 229376, blk + 245760,
            L(l, 3), L(l, 4), adjraw);
        if (newnode) {
            unsigned short* nblk = nwb + (size_t)l * 409600;
            node_gemm<<<dim3(NROWS / 64, 2), 256, 0, stream>>>(
                xin, nblk, nblk + 102400, nblk + 204800, nblk + 307200, nbuf);
            node_combine<<<B_, 320, 0, stream>>>(adjraw, nbuf, L(l, 6), L(l, 8),
                                                 L(l, 9), (float*)d_out);
        } else {
            topk_kernel<<<NROWS, 64, 0, stream>>>(adjraw, A);
            node_kernel<<<B_, 320, 0, stream>>>(xin, A, L(l, 5), L(l, 6), L(l, 7),
                                                L(l, 8), L(l, 9), (float*)d_out);
        }
    }
}

// Round 14
// 180.998 us; speedup vs baseline: 1.0411x; 1.0411x over previous
//
#include <hip/hip_runtime.h>
#include <math.h>

#define B_  128
#define N_  21
#define D_  300
#define NPAIRS 231                  // upper-tri incl diag
#define NPAIR_TOT (B_ * NPAIRS)     // 29568
#define GRID_E (NPAIR_TOT / 64)     // 462 blocks x 4 waves x 16 pairs
#define NROWS (B_ * N_)             // 2688
#define DP  320

typedef __attribute__((ext_vector_type(8))) short short8v;
typedef __attribute__((ext_vector_type(4))) float f32x4;

__device__ __forceinline__ float lrelu(float v) { return v > 0.f ? v : 0.01f * v; }

__device__ __forceinline__ unsigned short f2bf(float f) {
    unsigned u = __builtin_bit_cast(unsigned, f);
    u += 0x7FFFu + ((u >> 16) & 1u);
    return (unsigned short)(u >> 16);
}
__device__ __forceinline__ float bf2f(unsigned short h) {
    unsigned u = ((unsigned)h) << 16;
    return __builtin_bit_cast(float, u);
}

// ---------------------------------------------------------------------------
// One prep kernel: edge weights (2 layers) + node weights -> bf16 hi/lo.
__global__ __launch_bounds__(256) void prep_all(
    const float* __restrict__ e00, const float* __restrict__ e01, const float* __restrict__ e02,
    const float* __restrict__ e10, const float* __restrict__ e11, const float* __restrict__ e12,
    const float* __restrict__ n0n, const float* __restrict__ n0r,
    const float* __restrict__ n1n, const float* __restrict__ n1r,
    unsigned short* __restrict__ ewb, unsigned short* __restrict__ nwb, int do_node)
{
    int idx = blockIdx.x * 256 + threadIdx.x;   // grid 2624 -> 671744 exact
    float v; unsigned short *ph, *pl; int off;
    if (idx < 262144) {
        int l = idx >> 17;
        int t = idx & 131071;
        unsigned short* blk = ewb + (size_t)l * 262144;
        const float* w0 = l ? e10 : e00;
        const float* w1 = l ? e11 : e01;
        const float* w2 = l ? e12 : e02;
        if (t < 81920) {
            int n = t / 320, k = t - n * 320;
            v = (k < 300) ? w0[n * 300 + k] : 0.f;
            ph = blk; pl = blk + 81920; off = t;
        } else if (t < 114688) {
            int r = t - 81920; v = w1[r];
            ph = blk + 163840; pl = blk + 196608; off = r;
        } else {
            int r = t - 114688; v = w2[r];
            ph = blk + 229376; pl = blk + 245760; off = r;
        }
    } else {
        if (!do_node) return;
        int t = idx - 262144;                    // 0 .. 409599
        int l = t / 204800;
        int r = t - l * 204800;
        int mat = r / 102400;
        int q = r - mat * 102400;
        int n = q / 320, k = q - n * 320;
        const float* src = l ? (mat ? n1r : n1n) : (mat ? n0r : n0n);
        v = (n < 300 && k < 300) ? src[n * 300 + k] : 0.f;
        unsigned short* blk = nwb + (size_t)l * 409600;
        ph = blk + mat * 204800; pl = ph + 102400; off = q;
    }
    unsigned short hb = f2bf(v);
    ph[off] = hb; pl[off] = f2bf(v - bf2f(hb));
}

// ---------------------------------------------------------------------------
// 4-lane-group transpose (by value; verified rounds 6-12).
__device__ __forceinline__ short8v mk_frag(uint2 tlo, uint2 thi,
                                           int s1, int s2, bool hif)
{
    unsigned a0 = (unsigned)__shfl((int)tlo.x, s1);
    unsigned b0 = (unsigned)__shfl((int)thi.x, s1);
    unsigned a1 = (unsigned)__shfl((int)tlo.y, s1);
    unsigned b1 = (unsigned)__shfl((int)thi.y, s1);
    unsigned a2 = (unsigned)__shfl((int)tlo.x, s2);
    unsigned b2 = (unsigned)__shfl((int)thi.x, s2);
    unsigned a3 = (unsigned)__shfl((int)tlo.y, s2);
    unsigned b3 = (unsigned)__shfl((int)thi.y, s2);
    union { unsigned u[4]; short8v v; } r;
    r.u[0] = hif ? b0 : a0; r.u[1] = hif ? b1 : a1;
    r.u[2] = hif ? b2 : a2; r.u[3] = hif ? b3 : a3;
    return r.v;
}

// ---------------------------------------------------------------------------
// Edge MLP (round-11 proven, full bf16x3): 4 waves x 16 pairs; hi+lo weights
// staged per-k-chunk into LDS dbuf via global_load_lds; full unroll on G2/G3.
__global__ __launch_bounds__(256, 2) void edge_mfma(
    const float* __restrict__ x,
    const unsigned short* __restrict__ w0h, const unsigned short* __restrict__ w0l,
    const unsigned short* __restrict__ w1h, const unsigned short* __restrict__ w1l,
    const unsigned short* __restrict__ w2h, const unsigned short* __restrict__ w2l,
    const float* __restrict__ wo, const float* __restrict__ bo,
    float* __restrict__ adjraw)
{
    __shared__ __align__(16) unsigned short ldsW[2][16384];   // 2 x 32 KB

    const int tid  = threadIdx.x;
    const int lane = tid & 63;
    const int w    = tid >> 6;
    const int l15  = lane & 15;
    const int l4   = lane >> 4;

    const int p = blockIdx.x * 64 + w * 16 + l15;
    int bb = p / NPAIRS;
    int u  = p - bb * NPAIRS;
    int ii = 0;
    while (u >= N_ - ii) { u -= N_ - ii; ++ii; }
    int jj = ii + u;
    const float* xi = x + ((size_t)bb * N_ + ii) * D_;
    const float* xj = x + ((size_t)bb * N_ + jj) * D_;

    const int s1 = (lane & 15) | ((lane & 16) << 1);
    const int s2 = s1 + 16;
    const bool hif = (l4 >> 1) != 0;

    auto stage_g1 = [&](int c, int sel) {
        #pragma unroll
        for (int i = 0; i < 4; ++i) {
            const int tile = i * 4 + w;
            const size_t g = (size_t)(tile * 16 + l15) * 320 + c * 32 + l4 * 8;
            __builtin_amdgcn_global_load_lds((const unsigned int*)(w0h + g),
                (unsigned int*)(&ldsW[sel][tile * 512]), 16, 0, 0);
            __builtin_amdgcn_global_load_lds((const unsigned int*)(w0l + g),
                (unsigned int*)(&ldsW[sel][8192 + tile * 512]), 16, 0, 0);
        }
    };
    auto stage_g2 = [&](int c, int sel) {
        #pragma unroll
        for (int i = 0; i < 2; ++i) {
            const int tile = i * 4 + w;
            const size_t g = (size_t)(tile * 16 + l15) * 256 + c * 32 + l4 * 8;
            __builtin_amdgcn_global_load_lds((const unsigned int*)(w1h + g),
                (unsigned int*)(&ldsW[sel][tile * 512]), 16, 0, 0);
            __builtin_amdgcn_global_load_lds((const unsigned int*)(w1l + g),
                (unsigned int*)(&ldsW[sel][8192 + tile * 512]), 16, 0, 0);
        }
    };
    auto stage_g3 = [&](int c, int sel) {
        #pragma unroll
        for (int i = 0; i < 2; ++i) {
            const int tile = i * 4 + w;
            const size_t g = (size_t)(tile * 16 + l15) * 128 + c * 32 + l4 * 8;
            __builtin_amdgcn_global_load_lds((const unsigned int*)(w2h + g),
                (unsigned int*)(&ldsW[sel][tile * 512]), 16, 0, 0);
            __builtin_amdgcn_global_load_lds((const unsigned int*)(w2l + g),
                (unsigned int*)(&ldsW[sel][8192 + tile * 512]), 16, 0, 0);
        }
    };

    // ---------------- G1: h0 = w0 @ xij^T, K=320 (10 chunks) ----------------
    f32x4 acc[16];
    #pragma unroll
    for (int t = 0; t < 16; ++t) acc[t] = (f32x4){0.f, 0.f, 0.f, 0.f};

    stage_g1(0, 0);
    __syncthreads();

    #pragma unroll 1
    for (int c = 0; c < 10; ++c) {
        const int sel = c & 1;
        if (c < 9) stage_g1(c + 1, sel ^ 1);
        else       stage_g2(0, sel ^ 1);

        const int d0 = c * 32 + l4 * 8;
        float v[8];
        if (c < 9) {
            float4 a0 = *(const float4*)(xi + d0);
            float4 a1 = *(const float4*)(xi + d0 + 4);
            float4 b0 = *(const float4*)(xj + d0);
            float4 b1 = *(const float4*)(xj + d0 + 4);
            #pragma unroll
            for (int e = 0; e < 4; ++e) {
                v[e]     = expf(-fabsf((&a0.x)[e] - (&b0.x)[e]));
                v[4 + e] = expf(-fabsf((&a1.x)[e] - (&b1.x)[e]));
            }
        } else {
            #pragma unroll
            for (int e = 0; e < 8; ++e) {
                int d = d0 + e;
                v[e] = (d < D_) ? expf(-fabsf(xi[d] - xj[d])) : 0.f;
            }
        }
        short8v bh, bl;
        #pragma unroll
        for (int e = 0; e < 8; ++e) {
            unsigned short hb = f2bf(v[e]);
            bh[e] = (short)hb;
            bl[e] = (short)f2bf(v[e] - bf2f(hb));
        }

        #pragma unroll
        for (int t = 0; t < 16; ++t) {
            short8v wh = *(const short8v*)(&ldsW[sel][t * 512 + lane * 8]);
            short8v wl = *(const short8v*)(&ldsW[sel][8192 + t * 512 + lane * 8]);
            acc[t] = __builtin_amdgcn_mfma_f32_16x16x32_bf16(wh, bh, acc[t], 0, 0, 0);
            acc[t] = __builtin_amdgcn_mfma_f32_16x16x32_bf16(wh, bl, acc[t], 0, 0, 0);
            acc[t] = __builtin_amdgcn_mfma_f32_16x16x32_bf16(wl, bh, acc[t], 0, 0, 0);
        }
        __syncthreads();
    }

    uint2 hh[16], ll[16];
    #pragma unroll
    for (int t = 0; t < 16; ++t) {
        unsigned short h_[4], l_[4];
        #pragma unroll
        for (int r = 0; r < 4; ++r) {
            float f = lrelu(acc[t][r]);
            h_[r] = f2bf(f);
            l_[r] = f2bf(f - bf2f(h_[r]));
        }
        hh[t].x = (unsigned)h_[0] | ((unsigned)h_[1] << 16);
        hh[t].y = (unsigned)h_[2] | ((unsigned)h_[3] << 16);
        ll[t].x = (unsigned)l_[0] | ((unsigned)l_[1] << 16);
        ll[t].y = (unsigned)l_[2] | ((unsigned)l_[3] << 16);
    }

    // ---------------- G2: h1 = w1 @ h0^T, K=256 (8 chunks, FULL UNROLL) ----
    f32x4 acc2[8];
    #pragma unroll
    for (int t = 0; t < 8; ++t) acc2[t] = (f32x4){0.f, 0.f, 0.f, 0.f};

    #pragma unroll
    for (int ks = 0; ks < 8; ++ks) {
        const int sel = ks & 1;
        if (ks < 7) stage_g2(ks + 1, sel ^ 1);
        else        stage_g3(0, sel ^ 1);

        short8v bh = mk_frag(hh[2 * ks], hh[2 * ks + 1], s1, s2, hif);
        short8v bl = mk_frag(ll[2 * ks], ll[2 * ks + 1], s1, s2, hif);

        #pragma unroll
        for (int t = 0; t < 8; ++t) {
            short8v wh = *(const short8v*)(&ldsW[sel][t * 512 + lane * 8]);
            short8v wl = *(const short8v*)(&ldsW[sel][8192 + t * 512 + lane * 8]);
            acc2[t] = __builtin_amdgcn_mfma_f32_16x16x32_bf16(wh, bh, acc2[t], 0, 0, 0);
            acc2[t] = __builtin_amdgcn_mfma_f32_16x16x32_bf16(wh, bl, acc2[t], 0, 0, 0);
            acc2[t] = __builtin_amdgcn_mfma_f32_16x16x32_bf16(wl, bh, acc2[t], 0, 0, 0);
        }
        __syncthreads();
    }

    uint2 hh1[8], ll1[8];
    #pragma unroll
    for (int t = 0; t < 8; ++t) {
        unsigned short h_[4], l_[4];
        #pragma unroll
        for (int r = 0; r < 4; ++r) {
            float f = lrelu(acc2[t][r]);
            h_[r] = f2bf(f);
            l_[r] = f2bf(f - bf2f(h_[r]));
        }
        hh1[t].x = (unsigned)h_[0] | ((unsigned)h_[1] << 16);
        hh1[t].y = (unsigned)h_[2] | ((unsigned)h_[3] << 16);
        ll1[t].x = (unsigned)l_[0] | ((unsigned)l_[1] << 16);
        ll1[t].y = (unsigned)l_[2] | ((unsigned)l_[3] << 16);
    }

    // ---------------- G3: h2 = w2 @ h1^T, K=128 (4 chunks, FULL UNROLL) ----
    f32x4 acc3[8];
    #pragma unroll
    for (int t = 0; t < 8; ++t) acc3[t] = (f32x4){0.f, 0.f, 0.f, 0.f};

    #pragma unroll
    for (int ks = 0; ks < 4; ++ks) {
        const int sel = ks & 1;
        if (ks < 3) stage_g3(ks + 1, sel ^ 1);

        short8v bh = mk_frag(hh1[2 * ks], hh1[2 * ks + 1], s1, s2, hif);
        short8v bl = mk_frag(ll1[2 * ks], ll1[2 * ks + 1], s1, s2, hif);

        #pragma unroll
        for (int t = 0; t < 8; ++t) {
            short8v wh = *(const short8v*)(&ldsW[sel][t * 512 + lane * 8]);
            short8v wl = *(const short8v*)(&ldsW[sel][8192 + t * 512 + lane * 8]);
            acc3[t] = __builtin_amdgcn_mfma_f32_16x16x32_bf16(wh, bh, acc3[t], 0, 0, 0);
            acc3[t] = __builtin_amdgcn_mfma_f32_16x16x32_bf16(wh, bl, acc3[t], 0, 0, 0);
            acc3[t] = __builtin_amdgcn_mfma_f32_16x16x32_bf16(wl, bh, acc3[t], 0, 0, 0);
        }
        __syncthreads();
    }

    float ps = 0.f;
    #pragma unroll
    for (int t = 0; t < 8; ++t) {
        float4 wov = *(const float4*)(wo + t * 16 + l4 * 4);
        #pragma unroll
        for (int r = 0; r < 4; ++r)
            ps += lrelu(acc3[t][r]) * (&wov.x)[r];
    }
    ps += __shfl_xor(ps, 16);
    ps += __shfl_xor(ps, 32);
    if (l4 == 0) {
        float a = 1.f / (1.f + expf(-(ps + bo[0])));
        if (ii == jj) a = 0.f;
        adjraw[(size_t)bb * 441 + ii * 21 + jj] = a;
        adjraw[(size_t)bb * 441 + jj * 21 + ii] = a;
    }
}

// ---------------------------------------------------------------------------
// Node GEMM via MFMA (round-11 proven): 16-row M-blocks, grid (168, 2).
__global__ __launch_bounds__(256, 4) void node_gemm(
    const float* __restrict__ xin,
    const unsigned short* __restrict__ wnh, const unsigned short* __restrict__ wnl,
    const unsigned short* __restrict__ wrh, const unsigned short* __restrict__ wrl,
    float* __restrict__ nbuf)
{
    __shared__ __align__(16) unsigned short sxh[2][512], sxl[2][512];

    const int tid  = threadIdx.x;
    const int lane = tid & 63;
    const int w    = tid >> 6;
    const int l15  = lane & 15;
    const int l4   = lane >> 4;
    const int M0   = blockIdx.x * 16;
    const int mat  = blockIdx.y;

    const unsigned short* ah_base = mat ? wrh : wnh;
    const unsigned short* al_base = mat ? wrl : wnl;
    float* ob = nbuf + (size_t)mat * NROWS * DP;

    const int sm = tid >> 4;
    const int sk = (tid & 15) * 2;
    const float* xrow = xin + (size_t)(M0 + sm) * D_;
    const int sa = sm * 32 + (((sk >> 3) ^ ((sm >> 1) & 3)) << 3) + (sk & 7);
    const int xr_off = l15 * 32 + ((l4 ^ ((l15 >> 1) & 3)) << 3);

    f32x4 acc[5];
    #pragma unroll
    for (int t = 0; t < 5; ++t) acc[t] = (f32x4){0.f, 0.f, 0.f, 0.f};

    {
        float2 v = *(const float2*)(xrow + sk);
        unsigned short h0 = f2bf(v.x), h1 = f2bf(v.y);
        unsigned uh = (unsigned)h0 | ((unsigned)h1 << 16);
        unsigned ul = (unsigned)f2bf(v.x - bf2f(h0)) |
                      ((unsigned)f2bf(v.y - bf2f(h1)) << 16);
        *(unsigned*)(&sxh[0][sa]) = uh;
        *(unsigned*)(&sxl[0][sa]) = ul;
    }
    __syncthreads();

    #pragma unroll 1
    for (int c = 0; c < 10; ++c) {
        const int sel = c & 1;
        short8v wh[5], wl[5];
        const int kg = c * 32 + l4 * 8;
        #pragma unroll
        for (int t = 0; t < 5; ++t) {
            const size_t n = (size_t)((w * 5 + t) * 16 + l15);
            wh[t] = *(const short8v*)(ah_base + n * DP + kg);
            wl[t] = *(const short8v*)(al_base + n * DP + kg);
        }
        float2 xv; bool have = false;
        if (c < 9) {
            const int k0 = (c + 1) * 32 + sk;
            if (k0 < D_) { xv = *(const float2*)(xrow + k0); have = true; }
        }
        short8v bh = *(const short8v*)(sxh[sel] + xr_off);
        short8v bl = *(const short8v*)(sxl[sel] + xr_off);
        #pragma unroll
        for (int t = 0; t < 5; ++t) {
            acc[t] = __builtin_amdgcn_mfma_f32_16x16x32_bf16(wh[t], bh, acc[t], 0, 0, 0);
            acc[t] = __builtin_amdgcn_mfma_f32_16x16x32_bf16(wh[t], bl, acc[t], 0, 0, 0);
            acc[t] = __builtin_amdgcn_mfma_f32_16x16x32_bf16(wl[t], bh, acc[t], 0, 0, 0);
        }
        if (c < 9) {
            unsigned uh = 0, ul = 0;
            if (have) {
                unsigned short h0 = f2bf(xv.x), h1 = f2bf(xv.y);
                uh = (unsigned)h0 | ((unsigned)h1 << 16);
                ul = (unsigned)f2bf(xv.x - bf2f(h0)) |
                     ((unsigned)f2bf(xv.y - bf2f(h1)) << 16);
            }
            *(unsigned*)(&sxh[sel ^ 1][sa]) = uh;
            *(unsigned*)(&sxl[sel ^ 1][sa]) = ul;
        }
        __syncthreads();
    }

    #pragma unroll
    for (int t = 0; t < 5; ++t) {
        const int n0 = (w * 5 + t) * 16 + l4 * 4;
        float4 v;
        v.x = acc[t][0]; v.y = acc[t][1]; v.z = acc[t][2]; v.w = acc[t][3];
        *(float4*)(ob + (size_t)(M0 + l15) * DP + n0) = v;
    }
}

// ---------------------------------------------------------------------------
// Per-batch fused top-k + combine (round-12 proven): P panel read once per b.
__global__ __launch_bounds__(320) void node_combine(
    const float* __restrict__ adjraw, const float* __restrict__ nbuf,
    const float* __restrict__ bn, const float* __restrict__ br,
    const float* __restrict__ eemb, float* __restrict__ out)
{
    const int b = blockIdx.x;
    const int tid = threadIdx.x;
    __shared__ float sadj[N_][24];
    __shared__ float sA[N_][24];
    __shared__ float srs[N_];

    for (int it = tid; it < N_ * N_; it += 320) {
        int t = it / N_, s = it - (it / N_) * N_;
        sadj[t][s] = adjraw[(size_t)b * 441 + it];
    }
    __syncthreads();
    if (tid < N_) {
        unsigned used = 0;
        for (int r = 0; r < 5; ++r) {
            float best = -1.f; int bi = 0;
            for (int j = 0; j < N_; ++j) {
                if (used & (1u << j)) continue;
                if (sadj[tid][j] > best) { best = sadj[tid][j]; bi = j; }
            }
            used |= (1u << bi);
        }
        float rs = 0.f;
        for (int j = 0; j < N_; ++j) {
            float m = ((used >> j) & 1u) ? sadj[tid][j] : 0.f;
            sA[tid][j] = m; rs += m;
        }
        srs[tid] = rs;
    }
    __syncthreads();

    const int o = tid;
    if (o < D_) {
        const float* Pb = nbuf + (size_t)b * N_ * DP;
        const float* Rb = nbuf + (size_t)NROWS * DP + (size_t)b * N_ * DP;
        float pr[N_];
        #pragma unroll
        for (int s = 0; s < N_; ++s) pr[s] = Pb[(size_t)s * DP + o];
        const float bn_o = bn[o], br_o = br[o];
        const float add_o = bn_o + eemb[o];
        #pragma unroll
        for (int t = 0; t < N_; ++t) {
            float m = 0.f;
            #pragma unroll
            for (int s = 0; s < N_; ++s) m += sA[t][s] * pr[s];
            out[((size_t)b * N_ + t) * D_ + o] =
                lrelu((m + srs[t] * add_o) * 0.2f + Rb[(size_t)t * DP + o] + br_o);
        }
    }
}

// ---------------------------------------------------------------------------
// Fallback path (ws too small): top-k + fp32 node kernel
__global__ __launch_bounds__(64) void topk_kernel(
    const float* __restrict__ adjraw, float* __restrict__ A)
{
    const int row = blockIdx.x;
    const int lane = threadIdx.x;
    __shared__ float sadj[32];
    __shared__ unsigned s_used;
    if (lane < N_) sadj[lane] = adjraw[row * N_ + lane];
    __syncthreads();
    if (lane == 0) {
        unsigned used = 0;
        for (int r = 0; r < 5; ++r) {
            float best = -1.f; int bi = 0;
            for (int j = 0; j < N_; ++j) {
                if (used & (1u << j)) continue;
                if (sadj[j] > best) { best = sadj[j]; bi = j; }
            }
            used |= (1u << bi);
        }
        s_used = used;
    }
    __syncthreads();
    if (lane < N_)
        A[row * N_ + lane] = ((s_used >> lane) & 1u) ? sadj[lane] : 0.f;
}

__global__ __launch_bounds__(320) void node_kernel(
    const float* __restrict__ xin, const float* __restrict__ A,
    const float* __restrict__ wn, const float* __restrict__ bn,
    const float* __restrict__ wr, const float* __restrict__ br,
    const float* __restrict__ eemb, float* __restrict__ out)
{
    const int b = blockIdx.x;
    const int tid = threadIdx.x;
    __shared__ float sx[N_][304];
    __shared__ float sA[N_][24];
    __shared__ float srs[N_];

    const float* xb = xin + (size_t)b * N_ * D_;
    for (int it = tid; it < N_ * D_; it += 320) {
        int j = it / D_, d = it - (it / D_) * D_;
        sx[j][d] = xb[it];
    }
    for (int it = tid; it < N_ * N_; it += 320) {
        int t = it / N_, s = it - (it / N_) * N_;
        sA[t][s] = A[((size_t)b * N_ + t) * N_ + s];
    }
    __syncthreads();
    if (tid < N_) {
        float s = 0.f;
        #pragma unroll
        for (int j = 0; j < N_; ++j) s += sA[tid][j];
        srs[tid] = s;
    }
    __syncthreads();

    const int o = tid;
    if (o < D_) {
        float nacc[N_], racc[N_];
        #pragma unroll
        for (int j = 0; j < N_; ++j) { nacc[j] = 0.f; racc[j] = 0.f; }
        const float* wnr = wn + (size_t)o * D_;
        const float* wrr = wr + (size_t)o * D_;
        for (int k4 = 0; k4 < D_; k4 += 4) {
            float4 wn4 = *(const float4*)(wnr + k4);
            float4 wr4 = *(const float4*)(wrr + k4);
            #pragma unroll
            for (int j = 0; j < N_; ++j) {
                float4 xv = *(const float4*)(&sx[j][k4]);
                nacc[j] += wn4.x * xv.x; nacc[j] += wn4.y * xv.y;
                nacc[j] += wn4.z * xv.z; nacc[j] += wn4.w * xv.w;
                racc[j] += wr4.x * xv.x; racc[j] += wr4.y * xv.y;
                racc[j] += wr4.z * xv.z; racc[j] += wr4.w * xv.w;
            }
        }
        const float bn_o = bn[o], br_o = br[o], e0_o = eemb[o];
        const float add_o = bn_o + e0_o;
        #pragma unroll
        for (int t = 0; t < N_; ++t) {
            float m = 0.f;
            #pragma unroll
            for (int s = 0; s < N_; ++s) m += sA[t][s] * nacc[s];
            out[((size_t)b * N_ + t) * D_ + o] =
                lrelu((m + srs[t] * add_o) * 0.2f + racc[t] + br_o);
        }
    }
}

// ---------------------------------------------------------------------------
extern "C" void kernel_launch(void* const* d_in, const int* in_sizes, int n_in,
                              void* d_out, int out_size, void* d_ws, size_t ws_size,
                              hipStream_t stream)
{
    const float* x0 = (const float*)d_in[0];
    auto L = [&](int l, int k) { return (const float*)d_in[1 + l * 10 + k]; };

    // ws layout:
    //   adjraw @0        (225,792)
    //   A      @256KB    (225,792)               (fallback only)
    //   edge w @512KB    (2 x 512KB)             -> ends 1,572,864
    //   node w @1.5MB    (2 x 819,200)           -> ends 3,211,264
    //   nbuf   @3,211,264 (6,881,280)            -> ends 10,092,544
    float* adjraw = (float*)d_ws;
    float* A      = (float*)((char*)d_ws + 262144);
    unsigned short* ewb = (unsigned short*)((char*)d_ws + 524288);
    unsigned short* nwb = (unsigned short*)((char*)d_ws + 1572864);
    float* nbuf   = (float*)((char*)d_ws + 3211264);
    const size_t WS_NEED = 10092544;
    const bool newnode = (ws_size >= WS_NEED);

    prep_all<<<2624, 256, 0, stream>>>(
        L(0,0), L(0,1), L(0,2), L(1,0), L(1,1), L(1,2),
        L(0,5), L(0,7), L(1,5), L(1,7), ewb, nwb, newnode ? 1 : 0);

    for (int l = 0; l < 2; ++l) {
        const float* xin = (l == 0) ? x0 : (const float*)d_out;
        unsigned short* blk = ewb + (size_t)l * 262144;
        edge_mfma<<<GRID_E, 256, 0, stream>>>(xin,
            blk, blk + 81920, blk + 163840, blk + 196608, blk + 229376, blk + 245760,
            L(l, 3), L(l, 4), adjraw);
        if (newnode) {
            unsigned short* nblk = nwb + (size_t)l * 409600;
            node_gemm<<<dim3(NROWS / 16, 2), 256, 0, stream>>>(
                xin, nblk, nblk + 102400, nblk + 204800, nblk + 307200, nbuf);
            node_combine<<<B_, 320, 0, stream>>>(adjraw, nbuf, L(l, 6), L(l, 8),
                                                 L(l, 9), (float*)d_out);
        } else {
            topk_kernel<<<NROWS, 64, 0, stream>>>(adjraw, A);
            node_kernel<<<B_, 320, 0, stream>>>(xin, A, L(l, 5), L(l, 6), L(l, 7),
                                                L(l, 8), L(l, 9), (float*)d_out);
        }
    }
}

// Round 15
// 177.245 us; speedup vs baseline: 1.0631x; 1.0212x over previous
//
#include <hip/hip_runtime.h>
#include <math.h>

#define B_  128
#define N_  21
#define D_  300
#define NPAIRS 231                  // upper-tri incl diag
#define NPAIR_TOT (B_ * NPAIRS)     // 29568
#define GRID_E (NPAIR_TOT / 64)     // 462 edge blocks
#define GRID_N 336                  // 168 m-tiles x 2 mats
#define NROWS (B_ * N_)             // 2688
#define DP  320

typedef __attribute__((ext_vector_type(8))) short short8v;
typedef __attribute__((ext_vector_type(4))) float f32x4;

__device__ __forceinline__ float lrelu(float v) { return v > 0.f ? v : 0.01f * v; }

__device__ __forceinline__ unsigned short f2bf(float f) {
    unsigned u = __builtin_bit_cast(unsigned, f);
    u += 0x7FFFu + ((u >> 16) & 1u);
    return (unsigned short)(u >> 16);
}
__device__ __forceinline__ float bf2f(unsigned short h) {
    unsigned u = ((unsigned)h) << 16;
    return __builtin_bit_cast(float, u);
}

// ---------------------------------------------------------------------------
// One prep kernel: edge weights (2 layers) + node weights -> bf16 hi/lo.
__global__ __launch_bounds__(256) void prep_all(
    const float* __restrict__ e00, const float* __restrict__ e01, const float* __restrict__ e02,
    const float* __restrict__ e10, const float* __restrict__ e11, const float* __restrict__ e12,
    const float* __restrict__ n0n, const float* __restrict__ n0r,
    const float* __restrict__ n1n, const float* __restrict__ n1r,
    unsigned short* __restrict__ ewb, unsigned short* __restrict__ nwb, int do_node)
{
    int idx = blockIdx.x * 256 + threadIdx.x;   // grid 2624 -> 671744 exact
    float v; unsigned short *ph, *pl; int off;
    if (idx < 262144) {
        int l = idx >> 17;
        int t = idx & 131071;
        unsigned short* blk = ewb + (size_t)l * 262144;
        const float* w0 = l ? e10 : e00;
        const float* w1 = l ? e11 : e01;
        const float* w2 = l ? e12 : e02;
        if (t < 81920) {
            int n = t / 320, k = t - n * 320;
            v = (k < 300) ? w0[n * 300 + k] : 0.f;
            ph = blk; pl = blk + 81920; off = t;
        } else if (t < 114688) {
            int r = t - 81920; v = w1[r];
            ph = blk + 163840; pl = blk + 196608; off = r;
        } else {
            int r = t - 114688; v = w2[r];
            ph = blk + 229376; pl = blk + 245760; off = r;
        }
    } else {
        if (!do_node) return;
        int t = idx - 262144;                    // 0 .. 409599
        int l = t / 204800;
        int r = t - l * 204800;
        int mat = r / 102400;
        int q = r - mat * 102400;
        int n = q / 320, k = q - n * 320;
        const float* src = l ? (mat ? n1r : n1n) : (mat ? n0r : n0n);
        v = (n < 300 && k < 300) ? src[n * 300 + k] : 0.f;
        unsigned short* blk = nwb + (size_t)l * 409600;
        ph = blk + mat * 204800; pl = ph + 102400; off = q;
    }
    unsigned short hb = f2bf(v);
    ph[off] = hb; pl[off] = f2bf(v - bf2f(hb));
}

// ---------------------------------------------------------------------------
// 4-lane-group transpose (by value; verified rounds 6-14).
__device__ __forceinline__ short8v mk_frag(uint2 tlo, uint2 thi,
                                           int s1, int s2, bool hif)
{
    unsigned a0 = (unsigned)__shfl((int)tlo.x, s1);
    unsigned b0 = (unsigned)__shfl((int)thi.x, s1);
    unsigned a1 = (unsigned)__shfl((int)tlo.y, s1);
    unsigned b1 = (unsigned)__shfl((int)thi.y, s1);
    unsigned a2 = (unsigned)__shfl((int)tlo.x, s2);
    unsigned b2 = (unsigned)__shfl((int)thi.x, s2);
    unsigned a3 = (unsigned)__shfl((int)tlo.y, s2);
    unsigned b3 = (unsigned)__shfl((int)thi.y, s2);
    union { unsigned u[4]; short8v v; } r;
    r.u[0] = hif ? b0 : a0; r.u[1] = hif ? b1 : a1;
    r.u[2] = hif ? b2 : a2; r.u[3] = hif ? b3 : a3;
    return r.v;
}

// ---------------------------------------------------------------------------
// Edge body (round-11/14 proven, full bf16x3). lds = 2 x 16384 ushorts.
__device__ __forceinline__ void edge_body(
    unsigned short* lds, const float* __restrict__ x,
    const unsigned short* __restrict__ w0h, const unsigned short* __restrict__ w0l,
    const unsigned short* __restrict__ w1h, const unsigned short* __restrict__ w1l,
    const unsigned short* __restrict__ w2h, const unsigned short* __restrict__ w2l,
    const float* __restrict__ wo, const float* __restrict__ bo,
    float* __restrict__ adjraw, int bid)
{
    const int tid  = threadIdx.x;
    const int lane = tid & 63;
    const int w    = tid >> 6;
    const int l15  = lane & 15;
    const int l4   = lane >> 4;

    const int p = bid * 64 + w * 16 + l15;
    int bb = p / NPAIRS;
    int u  = p - bb * NPAIRS;
    int ii = 0;
    while (u >= N_ - ii) { u -= N_ - ii; ++ii; }
    int jj = ii + u;
    const float* xi = x + ((size_t)bb * N_ + ii) * D_;
    const float* xj = x + ((size_t)bb * N_ + jj) * D_;

    const int s1 = (lane & 15) | ((lane & 16) << 1);
    const int s2 = s1 + 16;
    const bool hif = (l4 >> 1) != 0;

    auto stage_g1 = [&](int c, int sel) {
        #pragma unroll
        for (int i = 0; i < 4; ++i) {
            const int tile = i * 4 + w;
            const size_t g = (size_t)(tile * 16 + l15) * 320 + c * 32 + l4 * 8;
            __builtin_amdgcn_global_load_lds((const unsigned int*)(w0h + g),
                (unsigned int*)(lds + sel * 16384 + tile * 512), 16, 0, 0);
            __builtin_amdgcn_global_load_lds((const unsigned int*)(w0l + g),
                (unsigned int*)(lds + sel * 16384 + 8192 + tile * 512), 16, 0, 0);
        }
    };
    auto stage_g2 = [&](int c, int sel) {
        #pragma unroll
        for (int i = 0; i < 2; ++i) {
            const int tile = i * 4 + w;
            const size_t g = (size_t)(tile * 16 + l15) * 256 + c * 32 + l4 * 8;
            __builtin_amdgcn_global_load_lds((const unsigned int*)(w1h + g),
                (unsigned int*)(lds + sel * 16384 + tile * 512), 16, 0, 0);
            __builtin_amdgcn_global_load_lds((const unsigned int*)(w1l + g),
                (unsigned int*)(lds + sel * 16384 + 8192 + tile * 512), 16, 0, 0);
        }
    };
    auto stage_g3 = [&](int c, int sel) {
        #pragma unroll
        for (int i = 0; i < 2; ++i) {
            const int tile = i * 4 + w;
            const size_t g = (size_t)(tile * 16 + l15) * 128 + c * 32 + l4 * 8;
            __builtin_amdgcn_global_load_lds((const unsigned int*)(w2h + g),
                (unsigned int*)(lds + sel * 16384 + tile * 512), 16, 0, 0);
            __builtin_amdgcn_global_load_lds((const unsigned int*)(w2l + g),
                (unsigned int*)(lds + sel * 16384 + 8192 + tile * 512), 16, 0, 0);
        }
    };

    // ---------------- G1: h0 = w0 @ xij^T, K=320 (10 chunks) ----------------
    f32x4 acc[16];
    #pragma unroll
    for (int t = 0; t < 16; ++t) acc[t] = (f32x4){0.f, 0.f, 0.f, 0.f};

    stage_g1(0, 0);
    __syncthreads();

    #pragma unroll 1
    for (int c = 0; c < 10; ++c) {
        const int sel = c & 1;
        if (c < 9) stage_g1(c + 1, sel ^ 1);
        else       stage_g2(0, sel ^ 1);

        const int d0 = c * 32 + l4 * 8;
        float v[8];
        if (c < 9) {
            float4 a0 = *(const float4*)(xi + d0);
            float4 a1 = *(const float4*)(xi + d0 + 4);
            float4 b0 = *(const float4*)(xj + d0);
            float4 b1 = *(const float4*)(xj + d0 + 4);
            #pragma unroll
            for (int e = 0; e < 4; ++e) {
                v[e]     = expf(-fabsf((&a0.x)[e] - (&b0.x)[e]));
                v[4 + e] = expf(-fabsf((&a1.x)[e] - (&b1.x)[e]));
            }
        } else {
            #pragma unroll
            for (int e = 0; e < 8; ++e) {
                int d = d0 + e;
                v[e] = (d < D_) ? expf(-fabsf(xi[d] - xj[d])) : 0.f;
            }
        }
        short8v bh, bl;
        #pragma unroll
        for (int e = 0; e < 8; ++e) {
            unsigned short hb = f2bf(v[e]);
            bh[e] = (short)hb;
            bl[e] = (short)f2bf(v[e] - bf2f(hb));
        }

        #pragma unroll
        for (int t = 0; t < 16; ++t) {
            short8v wh = *(const short8v*)(lds + sel * 16384 + t * 512 + lane * 8);
            short8v wl = *(const short8v*)(lds + sel * 16384 + 8192 + t * 512 + lane * 8);
            acc[t] = __builtin_amdgcn_mfma_f32_16x16x32_bf16(wh, bh, acc[t], 0, 0, 0);
            acc[t] = __builtin_amdgcn_mfma_f32_16x16x32_bf16(wh, bl, acc[t], 0, 0, 0);
            acc[t] = __builtin_amdgcn_mfma_f32_16x16x32_bf16(wl, bh, acc[t], 0, 0, 0);
        }
        __syncthreads();
    }

    uint2 hh[16], ll[16];
    #pragma unroll
    for (int t = 0; t < 16; ++t) {
        unsigned short h_[4], l_[4];
        #pragma unroll
        for (int r = 0; r < 4; ++r) {
            float f = lrelu(acc[t][r]);
            h_[r] = f2bf(f);
            l_[r] = f2bf(f - bf2f(h_[r]));
        }
        hh[t].x = (unsigned)h_[0] | ((unsigned)h_[1] << 16);
        hh[t].y = (unsigned)h_[2] | ((unsigned)h_[3] << 16);
        ll[t].x = (unsigned)l_[0] | ((unsigned)l_[1] << 16);
        ll[t].y = (unsigned)l_[2] | ((unsigned)l_[3] << 16);
    }

    // ---------------- G2: h1 = w1 @ h0^T, K=256 (8 chunks, FULL UNROLL) ----
    f32x4 acc2[8];
    #pragma unroll
    for (int t = 0; t < 8; ++t) acc2[t] = (f32x4){0.f, 0.f, 0.f, 0.f};

    #pragma unroll
    for (int ks = 0; ks < 8; ++ks) {
        const int sel = ks & 1;
        if (ks < 7) stage_g2(ks + 1, sel ^ 1);
        else        stage_g3(0, sel ^ 1);

        short8v bh = mk_frag(hh[2 * ks], hh[2 * ks + 1], s1, s2, hif);
        short8v bl = mk_frag(ll[2 * ks], ll[2 * ks + 1], s1, s2, hif);

        #pragma unroll
        for (int t = 0; t < 8; ++t) {
            short8v wh = *(const short8v*)(lds + sel * 16384 + t * 512 + lane * 8);
            short8v wl = *(const short8v*)(lds + sel * 16384 + 8192 + t * 512 + lane * 8);
            acc2[t] = __builtin_amdgcn_mfma_f32_16x16x32_bf16(wh, bh, acc2[t], 0, 0, 0);
            acc2[t] = __builtin_amdgcn_mfma_f32_16x16x32_bf16(wh, bl, acc2[t], 0, 0, 0);
            acc2[t] = __builtin_amdgcn_mfma_f32_16x16x32_bf16(wl, bh, acc2[t], 0, 0, 0);
        }
        __syncthreads();
    }

    uint2 hh1[8], ll1[8];
    #pragma unroll
    for (int t = 0; t < 8; ++t) {
        unsigned short h_[4], l_[4];
        #pragma unroll
        for (int r = 0; r < 4; ++r) {
            float f = lrelu(acc2[t][r]);
            h_[r] = f2bf(f);
            l_[r] = f2bf(f - bf2f(h_[r]));
        }
        hh1[t].x = (unsigned)h_[0] | ((unsigned)h_[1] << 16);
        hh1[t].y = (unsigned)h_[2] | ((unsigned)h_[3] << 16);
        ll1[t].x = (unsigned)l_[0] | ((unsigned)l_[1] << 16);
        ll1[t].y = (unsigned)l_[2] | ((unsigned)l_[3] << 16);
    }

    // ---------------- G3: h2 = w2 @ h1^T, K=128 (4 chunks, FULL UNROLL) ----
    f32x4 acc3[8];
    #pragma unroll
    for (int t = 0; t < 8; ++t) acc3[t] = (f32x4){0.f, 0.f, 0.f, 0.f};

    #pragma unroll
    for (int ks = 0; ks < 4; ++ks) {
        const int sel = ks & 1;
        if (ks < 3) stage_g3(ks + 1, sel ^ 1);

        short8v bh = mk_frag(hh1[2 * ks], hh1[2 * ks + 1], s1, s2, hif);
        short8v bl = mk_frag(ll1[2 * ks], ll1[2 * ks + 1], s1, s2, hif);

        #pragma unroll
        for (int t = 0; t < 8; ++t) {
            short8v wh = *(const short8v*)(lds + sel * 16384 + t * 512 + lane * 8);
            short8v wl = *(const short8v*)(lds + sel * 16384 + 8192 + t * 512 + lane * 8);
            acc3[t] = __builtin_amdgcn_mfma_f32_16x16x32_bf16(wh, bh, acc3[t], 0, 0, 0);
            acc3[t] = __builtin_amdgcn_mfma_f32_16x16x32_bf16(wh, bl, acc3[t], 0, 0, 0);
            acc3[t] = __builtin_amdgcn_mfma_f32_16x16x32_bf16(wl, bh, acc3[t], 0, 0, 0);
        }
        __syncthreads();
    }

    float ps = 0.f;
    #pragma unroll
    for (int t = 0; t < 8; ++t) {
        float4 wov = *(const float4*)(wo + t * 16 + l4 * 4);
        #pragma unroll
        for (int r = 0; r < 4; ++r)
            ps += lrelu(acc3[t][r]) * (&wov.x)[r];
    }
    ps += __shfl_xor(ps, 16);
    ps += __shfl_xor(ps, 32);
    if (l4 == 0) {
        float a = 1.f / (1.f + expf(-(ps + bo[0])));
        if (ii == jj) a = 0.f;
        adjraw[(size_t)bb * 441 + ii * 21 + jj] = a;
        adjraw[(size_t)bb * 441 + jj * 21 + ii] = a;
    }
}

// ---------------------------------------------------------------------------
// Node GEMM body (round-11/14 proven): 16-row M-block mb, one mat.
// lds usage: sxh[sel] = lds + sel*512; sxl[sel] = lds + 1024 + sel*512.
__device__ __forceinline__ void node_body(
    unsigned short* lds, const float* __restrict__ xin,
    const unsigned short* __restrict__ ah_base,
    const unsigned short* __restrict__ al_base,
    float* __restrict__ ob, int mb)
{
    const int tid  = threadIdx.x;
    const int lane = tid & 63;
    const int w    = tid >> 6;
    const int l15  = lane & 15;
    const int l4   = lane >> 4;
    const int M0   = mb * 16;

    const int sm = tid >> 4;
    const int sk = (tid & 15) * 2;
    const float* xrow = xin + (size_t)(M0 + sm) * D_;
    const int sa = sm * 32 + (((sk >> 3) ^ ((sm >> 1) & 3)) << 3) + (sk & 7);
    const int xr_off = l15 * 32 + ((l4 ^ ((l15 >> 1) & 3)) << 3);

    f32x4 acc[5];
    #pragma unroll
    for (int t = 0; t < 5; ++t) acc[t] = (f32x4){0.f, 0.f, 0.f, 0.f};

    {
        float2 v = *(const float2*)(xrow + sk);
        unsigned short h0 = f2bf(v.x), h1 = f2bf(v.y);
        unsigned uh = (unsigned)h0 | ((unsigned)h1 << 16);
        unsigned ul = (unsigned)f2bf(v.x - bf2f(h0)) |
                      ((unsigned)f2bf(v.y - bf2f(h1)) << 16);
        *(unsigned*)(lds + sa) = uh;
        *(unsigned*)(lds + 1024 + sa) = ul;
    }
    __syncthreads();

    #pragma unroll 1
    for (int c = 0; c < 10; ++c) {
        const int sel = c & 1;
        short8v wh[5], wl[5];
        const int kg = c * 32 + l4 * 8;
        #pragma unroll
        for (int t = 0; t < 5; ++t) {
            const size_t n = (size_t)((w * 5 + t) * 16 + l15);
            wh[t] = *(const short8v*)(ah_base + n * DP + kg);
            wl[t] = *(const short8v*)(al_base + n * DP + kg);
        }
        float2 xv; bool have = false;
        if (c < 9) {
            const int k0 = (c + 1) * 32 + sk;
            if (k0 < D_) { xv = *(const float2*)(xrow + k0); have = true; }
        }
        short8v bh = *(const short8v*)(lds + sel * 512 + xr_off);
        short8v bl = *(const short8v*)(lds + 1024 + sel * 512 + xr_off);
        #pragma unroll
        for (int t = 0; t < 5; ++t) {
            acc[t] = __builtin_amdgcn_mfma_f32_16x16x32_bf16(wh[t], bh, acc[t], 0, 0, 0);
            acc[t] = __builtin_amdgcn_mfma_f32_16x16x32_bf16(wh[t], bl, acc[t], 0, 0, 0);
            acc[t] = __builtin_amdgcn_mfma_f32_16x16x32_bf16(wl[t], bh, acc[t], 0, 0, 0);
        }
        if (c < 9) {
            unsigned uh = 0, ul = 0;
            if (have) {
                unsigned short h0 = f2bf(xv.x), h1 = f2bf(xv.y);
                uh = (unsigned)h0 | ((unsigned)h1 << 16);
                ul = (unsigned)f2bf(xv.x - bf2f(h0)) |
                     ((unsigned)f2bf(xv.y - bf2f(h1)) << 16);
            }
            *(unsigned*)(lds + (sel ^ 1) * 512 + sa) = uh;
            *(unsigned*)(lds + 1024 + (sel ^ 1) * 512 + sa) = ul;
        }
        __syncthreads();
    }

    #pragma unroll
    for (int t = 0; t < 5; ++t) {
        const int n0 = (w * 5 + t) * 16 + l4 * 4;
        float4 v;
        v.x = acc[t][0]; v.y = acc[t][1]; v.z = acc[t][2]; v.w = acc[t][3];
        *(float4*)(ob + (size_t)(M0 + l15) * DP + n0) = v;
    }
}

// ---------------------------------------------------------------------------
// Fat kernel: edge blocks [0, GRID_E) + node blocks [GRID_E, GRID_E+GRID_N).
// Edge and node GEMMs are data-independent (both read only xin) -> co-resident
// blocks overlap LDS-bound (edge) with L2-bound (node) work.
__global__ __launch_bounds__(256, 2) void fused_en(
    const float* __restrict__ x,
    const unsigned short* __restrict__ ew,      // edge weight block (layer)
    const float* __restrict__ wo, const float* __restrict__ bo,
    float* __restrict__ adjraw,
    const unsigned short* __restrict__ nw,      // node weight block (layer)
    float* __restrict__ nbuf)
{
    __shared__ __align__(16) unsigned short lds[2 * 16384];
    if (blockIdx.x < GRID_E) {
        edge_body(lds, x, ew, ew + 81920, ew + 163840, ew + 196608,
                  ew + 229376, ew + 245760, wo, bo, adjraw, blockIdx.x);
    } else {
        const int nb = blockIdx.x - GRID_E;     // 0..335
        const int mat = nb / 168;
        const int mb  = nb - mat * 168;
        const unsigned short* base = nw + (size_t)mat * 204800;
        node_body(lds, x, base, base + 102400,
                  nbuf + (size_t)mat * NROWS * DP, mb);
    }
}

// ---------------------------------------------------------------------------
// Standalone edge kernel (fallback path only).
__global__ __launch_bounds__(256, 2) void edge_mfma(
    const float* __restrict__ x,
    const unsigned short* __restrict__ ew,
    const float* __restrict__ wo, const float* __restrict__ bo,
    float* __restrict__ adjraw)
{
    __shared__ __align__(16) unsigned short lds[2 * 16384];
    edge_body(lds, x, ew, ew + 81920, ew + 163840, ew + 196608,
              ew + 229376, ew + 245760, wo, bo, adjraw, blockIdx.x);
}

// ---------------------------------------------------------------------------
// Per-batch fused top-k + combine (round-12 proven): P panel read once per b.
__global__ __launch_bounds__(320) void node_combine(
    const float* __restrict__ adjraw, const float* __restrict__ nbuf,
    const float* __restrict__ bn, const float* __restrict__ br,
    const float* __restrict__ eemb, float* __restrict__ out)
{
    const int b = blockIdx.x;
    const int tid = threadIdx.x;
    __shared__ float sadj[N_][24];
    __shared__ float sA[N_][24];
    __shared__ float srs[N_];

    for (int it = tid; it < N_ * N_; it += 320) {
        int t = it / N_, s = it - (it / N_) * N_;
        sadj[t][s] = adjraw[(size_t)b * 441 + it];
    }
    __syncthreads();
    if (tid < N_) {
        unsigned used = 0;
        for (int r = 0; r < 5; ++r) {
            float best = -1.f; int bi = 0;
            for (int j = 0; j < N_; ++j) {
                if (used & (1u << j)) continue;
                if (sadj[tid][j] > best) { best = sadj[tid][j]; bi = j; }
            }
            used |= (1u << bi);
        }
        float rs = 0.f;
        for (int j = 0; j < N_; ++j) {
            float m = ((used >> j) & 1u) ? sadj[tid][j] : 0.f;
            sA[tid][j] = m; rs += m;
        }
        srs[tid] = rs;
    }
    __syncthreads();

    const int o = tid;
    if (o < D_) {
        const float* Pb = nbuf + (size_t)b * N_ * DP;
        const float* Rb = nbuf + (size_t)NROWS * DP + (size_t)b * N_ * DP;
        float pr[N_];
        #pragma unroll
        for (int s = 0; s < N_; ++s) pr[s] = Pb[(size_t)s * DP + o];
        const float bn_o = bn[o], br_o = br[o];
        const float add_o = bn_o + eemb[o];
        #pragma unroll
        for (int t = 0; t < N_; ++t) {
            float m = 0.f;
            #pragma unroll
            for (int s = 0; s < N_; ++s) m += sA[t][s] * pr[s];
            out[((size_t)b * N_ + t) * D_ + o] =
                lrelu((m + srs[t] * add_o) * 0.2f + Rb[(size_t)t * DP + o] + br_o);
        }
    }
}

// ---------------------------------------------------------------------------
// Fallback path (ws too small): top-k + fp32 node kernel
__global__ __launch_bounds__(64) void topk_kernel(
    const float* __restrict__ adjraw, float* __restrict__ A)
{
    const int row = blockIdx.x;
    const int lane = threadIdx.x;
    __shared__ float sadj[32];
    __shared__ unsigned s_used;
    if (lane < N_) sadj[lane] = adjraw[row * N_ + lane];
    __syncthreads();
    if (lane == 0) {
        unsigned used = 0;
        for (int r = 0; r < 5; ++r) {
            float best = -1.f; int bi = 0;
            for (int j = 0; j < N_; ++j) {
                if (used & (1u << j)) continue;
                if (sadj[j] > best) { best = sadj[j]; bi = j; }
            }
            used |= (1u << bi);
        }
        s_used = used;
    }
    __syncthreads();
    if (lane < N_)
        A[row * N_ + lane] = ((s_used >> lane) & 1u) ? sadj[lane] : 0.f;
}

__global__ __launch_bounds__(320) void node_kernel(
    const float* __restrict__ xin, const float* __restrict__ A,
    const float* __restrict__ wn, const float* __restrict__ bn,
    const float* __restrict__ wr, const float* __restrict__ br,
    const float* __restrict__ eemb, float* __restrict__ out)
{
    const int b = blockIdx.x;
    const int tid = threadIdx.x;
    __shared__ float sx[N_][304];
    __shared__ float sA[N_][24];
    __shared__ float srs[N_];

    const float* xb = xin + (size_t)b * N_ * D_;
    for (int it = tid; it < N_ * D_; it += 320) {
        int j = it / D_, d = it - (it / D_) * D_;
        sx[j][d] = xb[it];
    }
    for (int it = tid; it < N_ * N_; it += 320) {
        int t = it / N_, s = it - (it / N_) * N_;
        sA[t][s] = A[((size_t)b * N_ + t) * N_ + s];
    }
    __syncthreads();
    if (tid < N_) {
        float s = 0.f;
        #pragma unroll
        for (int j = 0; j < N_; ++j) s += sA[tid][j];
        srs[tid] = s;
    }
    __syncthreads();

    const int o = tid;
    if (o < D_) {
        float nacc[N_], racc[N_];
        #pragma unroll
        for (int j = 0; j < N_; ++j) { nacc[j] = 0.f; racc[j] = 0.f; }
        const float* wnr = wn + (size_t)o * D_;
        const float* wrr = wr + (size_t)o * D_;
        for (int k4 = 0; k4 < D_; k4 += 4) {
            float4 wn4 = *(const float4*)(wnr + k4);
            float4 wr4 = *(const float4*)(wrr + k4);
            #pragma unroll
            for (int j = 0; j < N_; ++j) {
                float4 xv = *(const float4*)(&sx[j][k4]);
                nacc[j] += wn4.x * xv.x; nacc[j] += wn4.y * xv.y;
                nacc[j] += wn4.z * xv.z; nacc[j] += wn4.w * xv.w;
                racc[j] += wr4.x * xv.x; racc[j] += wr4.y * xv.y;
                racc[j] += wr4.z * xv.z; racc[j] += wr4.w * xv.w;
            }
        }
        const float bn_o = bn[o], br_o = br[o], e0_o = eemb[o];
        const float add_o = bn_o + e0_o;
        #pragma unroll
        for (int t = 0; t < N_; ++t) {
            float m = 0.f;
            #pragma unroll
            for (int s = 0; s < N_; ++s) m += sA[t][s] * nacc[s];
            out[((size_t)b * N_ + t) * D_ + o] =
                lrelu((m + srs[t] * add_o) * 0.2f + racc[t] + br_o);
        }
    }
}

// ---------------------------------------------------------------------------
extern "C" void kernel_launch(void* const* d_in, const int* in_sizes, int n_in,
                              void* d_out, int out_size, void* d_ws, size_t ws_size,
                              hipStream_t stream)
{
    const float* x0 = (const float*)d_in[0];
    auto L = [&](int l, int k) { return (const float*)d_in[1 + l * 10 + k]; };

    // ws layout:
    //   adjraw @0        (225,792)
    //   A      @256KB    (225,792)               (fallback only)
    //   edge w @512KB    (2 x 512KB)             -> ends 1,572,864
    //   node w @1.5MB    (2 x 819,200)           -> ends 3,211,264
    //   nbuf   @3,211,264 (6,881,280)            -> ends 10,092,544
    float* adjraw = (float*)d_ws;
    float* A      = (float*)((char*)d_ws + 262144);
    unsigned short* ewb = (unsigned short*)((char*)d_ws + 524288);
    unsigned short* nwb = (unsigned short*)((char*)d_ws + 1572864);
    float* nbuf   = (float*)((char*)d_ws + 3211264);
    const size_t WS_NEED = 10092544;
    const bool newnode = (ws_size >= WS_NEED);

    prep_all<<<2624, 256, 0, stream>>>(
        L(0,0), L(0,1), L(0,2), L(1,0), L(1,1), L(1,2),
        L(0,5), L(0,7), L(1,5), L(1,7), ewb, nwb, newnode ? 1 : 0);

    for (int l = 0; l < 2; ++l) {
        const float* xin = (l == 0) ? x0 : (const float*)d_out;
        unsigned short* blk = ewb + (size_t)l * 262144;
        if (newnode) {
            unsigned short* nblk = nwb + (size_t)l * 409600;
            fused_en<<<GRID_E + GRID_N, 256, 0, stream>>>(
                xin, blk, L(l, 3), L(l, 4), adjraw, nblk, nbuf);
            node_combine<<<B_, 320, 0, stream>>>(adjraw, nbuf, L(l, 6), L(l, 8),
                                                 L(l, 9), (float*)d_out);
        } else {
            edge_mfma<<<GRID_E, 256, 0, stream>>>(xin, blk, L(l, 3), L(l, 4), adjraw);
            topk_kernel<<<NROWS, 64, 0, stream>>>(adjraw, A);
            node_kernel<<<B_, 320, 0, stream>>>(xin, A, L(l, 5), L(l, 6), L(l, 7),
                                                L(l, 8), L(l, 9), (float*)d_out);
        }
    }
}